// Round 3
// baseline (735.454 us; speedup 1.0000x reference)
//
#include <hip/hip_runtime.h>

// ---------------------------------------------------------------------------
// (B,T,D)=(4,8192,1024), TREE_DEPTH=10, NUM_NODES=1023.
// Level 9 masked out; leaves = mean-8 of x[:, :4096, :] -> nodes 511..1022.
// Level L (8..0): GEMM R=4<<L rows, K=2048, N=1024; A-row = contiguous
// children pair of bf16 states; B = W_proj (1024x2048, K-contiguous, NT).
// All levels via one dbuf MFMA kernel (BK=128, 2-deep LDS pipeline).
// ---------------------------------------------------------------------------

#define NODES 1023
#define DIM   1024
#define K2    2048
#define NCHUNK 64

typedef short short8 __attribute__((ext_vector_type(8)));
typedef float floatx4 __attribute__((ext_vector_type(4)));

__device__ __forceinline__ unsigned short f2bf(float f) {
    unsigned u = __float_as_uint(f);
    unsigned r = ((u >> 16) & 1u) + 0x7fffu;
    return (unsigned short)((u + r) >> 16);
}

#define GLD16(g, l)                                                            \
    __builtin_amdgcn_global_load_lds(                                          \
        (const __attribute__((address_space(1))) void*)(g),                    \
        (__attribute__((address_space(3))) void*)(l), 16, 0, 0)

// --------------------------- W -> bf16 conversion ---------------------------
__global__ __launch_bounds__(256) void k_cvt_w(const float* __restrict__ W,
                                               unsigned short* __restrict__ Wb) {
    int i = (blockIdx.x * 256 + threadIdx.x) * 4;
    float4 v = *(const float4*)(W + i);
    ushort4 o;
    o.x = f2bf(v.x); o.y = f2bf(v.y); o.z = f2bf(v.z); o.w = f2bf(v.w);
    *(ushort4*)(Wb + i) = o;
}

// --------------------------------- leaves -----------------------------------
__global__ __launch_bounds__(256) void k_leaves(const float* __restrict__ x,
                                                float* __restrict__ Sf,
                                                unsigned short* __restrict__ Sb) {
    int leaf = blockIdx.x;
    int b = blockIdx.y;
    int d = threadIdx.x * 4;
    const float* xp = x + ((size_t)b * 8192 + (size_t)leaf * 8) * DIM + d;
    float4 s = {0.f, 0.f, 0.f, 0.f};
#pragma unroll
    for (int i = 0; i < 8; ++i) {
        float4 v = *(const float4*)(xp + (size_t)i * DIM);
        s.x += v.x; s.y += v.y; s.z += v.z; s.w += v.w;
    }
    s.x *= 0.125f; s.y *= 0.125f; s.z *= 0.125f; s.w *= 0.125f;
    size_t o = ((size_t)b * NODES + 511 + leaf) * DIM + d;
    *(float4*)(Sf + o) = s;
    ushort4 ob; ob.x = f2bf(s.x); ob.y = f2bf(s.y); ob.z = f2bf(s.z); ob.w = f2bf(s.w);
    *(ushort4*)(Sb + o) = ob;
}

// -------------------- MFMA level kernel, all levels 8..0 ---------------------
// 128x128 tile, BK=128, double-buffered LDS (2 x 64 KB), 16 K-iters, 1 barrier
// per iter.  Rows beyond R are clamped (redundant compute, masked at store).
__global__ __launch_bounds__(256) void k_level_mfma(
    const unsigned short* __restrict__ SbIn, const unsigned short* __restrict__ Wb,
    const float* __restrict__ bt, float* __restrict__ Sf,
    unsigned short* __restrict__ SbOut, int L, int R) {
    const int lvl_start = (1 << L) - 1;
    const int child_start = (2 << L) - 1;
    const int mask = (1 << L) - 1;

    __shared__ unsigned short Al[2][128 * 128];
    __shared__ unsigned short Bl[2][128 * 128];

    const int t = threadIdx.x;
    const int lane = t & 63;
    const int w = t >> 6;
    const int wm = w >> 1, wn = w & 1;
    const int bm = blockIdx.y, bn = blockIdx.x;

    // staging geometry: pass p covers rows p*16..p*16+15 of the 128x128 tile;
    // wave w covers rows p*16 + w*4 + (lane>>4); col (lane&15)*8.
    const int srow = w * 4 + (lane >> 4);       // 0..15 within pass
    const int scol = (lane & 15) * 8;           // 0..120

    // per-pass source row precompute for A (depends on level indexing)
    const unsigned short* asrc[8];
    const unsigned short* bsrc[8];
#pragma unroll
    for (int p = 0; p < 8; ++p) {
        int rg = bm * 128 + p * 16 + srow;
        int rc = rg < R ? rg : R - 1;
        int bb = rc >> L;
        int nl = rc & mask;
        asrc[p] = SbIn + ((size_t)bb * NODES + child_start + 2 * nl) * DIM + scol;
        int rb = bn * 128 + p * 16 + srow;
        bsrc[p] = Wb + (size_t)rb * K2 + scol;
    }

#define STAGE(buf, k0)                                                         \
    do {                                                                       \
        _Pragma("unroll") for (int p = 0; p < 8; ++p) {                        \
            GLD16(asrc[p] + (k0), &Al[buf][(p * 16 + w * 4) * 128]);           \
            GLD16(bsrc[p] + (k0), &Bl[buf][(p * 16 + w * 4) * 128]);           \
        }                                                                      \
    } while (0)

    floatx4 acc[4][4];
#pragma unroll
    for (int i = 0; i < 4; ++i)
#pragma unroll
        for (int j = 0; j < 4; ++j) acc[i][j] = (floatx4){0.f, 0.f, 0.f, 0.f};

    STAGE(0, 0);

    const int KT = K2 / 128;  // 16
    for (int kt = 0; kt < KT; ++kt) {
        __syncthreads();  // current buffer staged (barrier drains vmcnt)
        int cur = kt & 1;
        if (kt + 1 < KT) STAGE(1 - cur, (kt + 1) * 128);
#pragma unroll
        for (int ks = 0; ks < 4; ++ks) {
            short8 af[4], bfr[4];
#pragma unroll
            for (int i = 0; i < 4; ++i) {
                af[i] = *(const short8*)&Al[cur][(wm * 64 + i * 16 + (lane & 15)) * 128 +
                                                 ks * 32 + (lane >> 4) * 8];
                bfr[i] = *(const short8*)&Bl[cur][(wn * 64 + i * 16 + (lane & 15)) * 128 +
                                                  ks * 32 + (lane >> 4) * 8];
            }
#pragma unroll
            for (int i = 0; i < 4; ++i)
#pragma unroll
                for (int j = 0; j < 4; ++j)
                    acc[i][j] = __builtin_amdgcn_mfma_f32_16x16x32_bf16(
                        af[i], bfr[j], acc[i][j], 0, 0, 0);
        }
    }
#undef STAGE

    // ---- epilogue: gate by bt[L], write fp32 + bf16 states ----
#pragma unroll
    for (int i = 0; i < 4; ++i)
#pragma unroll
        for (int j = 0; j < 4; ++j)
#pragma unroll
            for (int r = 0; r < 4; ++r) {
                int m = bm * 128 + wm * 64 + i * 16 + (lane >> 4) * 4 + r;
                int n = bn * 128 + wn * 64 + j * 16 + (lane & 15);
                if (m < R) {
                    float v = acc[i][j][r];
                    float u = v - bt[L * DIM + n];
                    float o = (u > 0.f) ? v : 0.f;
                    int bb = m >> L;
                    int nl = m & mask;
                    size_t idx = ((size_t)bb * NODES + lvl_start + nl) * DIM + n;
                    Sf[idx] = o;
                    SbOut[idx] = f2bf(o);
                }
            }
}

// ---------------- softmax mixture, phase A: partial sums per chunk -----------
__global__ __launch_bounds__(256) void k_mixture_part(const float* __restrict__ nw,
                                                      const float* __restrict__ Sf,
                                                      float* __restrict__ part) {
    int d = blockIdx.x * 256 + threadIdx.x;  // 0..1023
    int c = blockIdx.y;
    int n0i = c * 16;
    int n1i = n0i + 16 < NODES ? n0i + 16 : NODES;
    float denom = 0.f, s0 = 0.f, s1 = 0.f, s2 = 0.f, s3 = 0.f;
    for (int n = n0i; n < n1i; ++n) {
        float wv = __expf(nw[(size_t)n * DIM + d]);
        denom += wv;
        s0 += wv * Sf[((size_t)0 * NODES + n) * DIM + d];
        s1 += wv * Sf[((size_t)1 * NODES + n) * DIM + d];
        s2 += wv * Sf[((size_t)2 * NODES + n) * DIM + d];
        s3 += wv * Sf[((size_t)3 * NODES + n) * DIM + d];
    }
    size_t base = ((size_t)c * 5) * DIM + d;
    part[base]           = denom;
    part[base + 1 * DIM] = s0;
    part[base + 2 * DIM] = s1;
    part[base + 3 * DIM] = s2;
    part[base + 4 * DIM] = s3;
}

// ---------------- softmax mixture, phase B: reduce chunks --------------------
__global__ __launch_bounds__(256) void k_mixture_red(const float* __restrict__ part,
                                                     float* __restrict__ mix) {
    int d = blockIdx.x * 256 + threadIdx.x;  // 0..1023
    float denom = 0.f, s0 = 0.f, s1 = 0.f, s2 = 0.f, s3 = 0.f;
#pragma unroll 8
    for (int c = 0; c < NCHUNK; ++c) {
        size_t base = ((size_t)c * 5) * DIM + d;
        denom += part[base];
        s0 += part[base + 1 * DIM];
        s1 += part[base + 2 * DIM];
        s2 += part[base + 3 * DIM];
        s3 += part[base + 4 * DIM];
    }
    float inv = 1.f / denom;
    mix[0 * DIM + d] = s0 * inv;
    mix[1 * DIM + d] = s1 * inv;
    mix[2 * DIM + d] = s2 * inv;
    mix[3 * DIM + d] = s3 * inv;
}

// --------------------- out = rmsnorm(x + mixture) * rms_w --------------------
__global__ __launch_bounds__(256) void k_final(const float* __restrict__ x,
                                               const float* __restrict__ mix,
                                               const float* __restrict__ rw,
                                               float* __restrict__ out) {
    int row = blockIdx.x;       // b*8192 + t
    int b = row >> 13;
    size_t base = (size_t)row * DIM;
    int t = threadIdx.x;
    float4 xv = *(const float4*)(x + base + t * 4);
    float4 mv = *(const float4*)(mix + b * DIM + t * 4);
    float4 v = {xv.x + mv.x, xv.y + mv.y, xv.z + mv.z, xv.w + mv.w};
    float ss = v.x * v.x + v.y * v.y + v.z * v.z + v.w * v.w;
#pragma unroll
    for (int o = 32; o > 0; o >>= 1) ss += __shfl_xor(ss, o, 64);
    __shared__ float wsum[4];
    int lane = t & 63, wv_ = t >> 6;
    if (lane == 0) wsum[wv_] = ss;
    __syncthreads();
    float tot = wsum[0] + wsum[1] + wsum[2] + wsum[3];
    float inv = 1.f / sqrtf(tot * (1.f / 1024.f) + 1.1920929e-7f);
    float4 rwv = *(const float4*)(rw + t * 4);
    float4 o4 = {v.x * inv * rwv.x, v.y * inv * rwv.y, v.z * inv * rwv.z,
                 v.w * inv * rwv.w};
    *(float4*)(out + base + t * 4) = o4;
}

// ----------------------------------------------------------------------------
extern "C" void kernel_launch(void* const* d_in, const int* in_sizes, int n_in,
                              void* d_out, int out_size, void* d_ws, size_t ws_size,
                              hipStream_t stream) {
    (void)in_sizes; (void)n_in; (void)out_size; (void)ws_size;
    const float* x  = (const float*)d_in[0];
    const float* W  = (const float*)d_in[1];
    const float* nw = (const float*)d_in[2];
    const float* bt = (const float*)d_in[3];
    // d_in[4] = as_w, multiplied by 0.0 in reference -> unused
    const float* rw = (const float*)d_in[5];
    float* out = (float*)d_out;

    char* ws = (char*)d_ws;
    const size_t SF_BYTES = (size_t)4 * NODES * DIM * 4;   // 16,760,832
    const size_t SB_BYTES = (size_t)4 * NODES * DIM * 2;   //  8,380,416
    const size_t WB_BYTES = (size_t)K2 * DIM * 2;          //  4,194,304
    const size_t MIX_BYTES = (size_t)4 * DIM * 4;          //     16,384
    float* Sf = (float*)ws;
    unsigned short* Sb = (unsigned short*)(ws + SF_BYTES);
    unsigned short* Wb = (unsigned short*)(ws + SF_BYTES + SB_BYTES);
    float* mix = (float*)(ws + SF_BYTES + SB_BYTES + WB_BYTES);
    float* part = (float*)(ws + SF_BYTES + SB_BYTES + WB_BYTES + MIX_BYTES);

    k_cvt_w<<<2048, 256, 0, stream>>>(W, Wb);
    k_leaves<<<dim3(512, 4), 256, 0, stream>>>(x, Sf, Sb);

    for (int L = 8; L >= 0; --L) {
        int R = 4 << L;
        dim3 grid(8, (R + 127) / 128);
        k_level_mfma<<<grid, 256, 0, stream>>>(Sb, Wb, bt, Sf, Sb, L, R);
    }
    k_mixture_part<<<dim3(4, NCHUNK), 256, 0, stream>>>(nw, Sf, part);
    k_mixture_red<<<4, 256, 0, stream>>>(part, mix);
    k_final<<<32768, 256, 0, stream>>>(x, mix, rw, out);
}